// Round 3
// baseline (44.086 us; speedup 1.0000x reference)
//
#include <hip/hip_runtime.h>
#include <hip/hip_bf16.h>
#include <stdint.h>

// LS2T order-4 iterated sums. B=32,T=2048,F=128,m=64,C=10.
// R3: no LDS M-staging. Wave = (seg 64t, nt 16m-slice). Row-interleaved t
// mapping (A-row i, sub s -> t = i*4+s) makes each lane's MFMA accumulator
// elements a contiguous 16-t range; per-lane f32 micro-scan + 2-step
// shfl_xor butterfly (per-level ordered monoid merge) -> 64-t aggregates.
// X tile converted to bf16 once per block into 16KB swizzled LDS.

typedef __attribute__((ext_vector_type(8))) short short8;
typedef __attribute__((ext_vector_type(4))) float f32x4;

#define T_ 2048
#define F_ 128
#define M_ 64
#define NTILE 40
#define SEGS 32

__device__ __forceinline__ unsigned short f2bf(float x){
  unsigned int u = __float_as_uint(x);
  u += 0x7FFFu + ((u>>16)&1u);       // RNE
  return (unsigned short)(u>>16);
}

// ---- Kernel 1: W fp32 -> bf16 MFMA B-fragments ----
__global__ __launch_bounds__(256) void prep_w_k(const float* __restrict__ Wk,
                                                uint4* __restrict__ wsw){
  int g = blockIdx.x*256 + threadIdx.x;
  if (g >= NTILE*4*64) return;
  int l  = g & 63;
  int kk = (g >> 6) & 3;
  int n  = g >> 8;
  int cm = n*16 + (l & 15);
  int c  = cm >> 6, mm = cm & 63;
  int kb = kk*32 + (l>>4)*8;
  unsigned short v[8];
  #pragma unroll
  for (int j=0;j<8;++j) v[j] = f2bf(Wk[((c*F_) + kb + j)*M_ + mm]);
  uint4 o;
  o.x = (unsigned)v[0] | ((unsigned)v[1]<<16);
  o.y = (unsigned)v[2] | ((unsigned)v[3]<<16);
  o.z = (unsigned)v[4] | ((unsigned)v[5]<<16);
  o.w = (unsigned)v[6] | ((unsigned)v[7]<<16);
  wsw[g] = o;
}

// MFMA fill: acc[c][s] = sum_kk X_frag[s][kk] * W_frag[BC+c][nt][kk]
template<int NC, int BC>
__device__ __forceinline__ void mfma_fill(f32x4 (&acc)[NC][4],
    const char* xs, const short8* __restrict__ wfrag,
    const int* rbase, const int* foff, int nt, int l){
  #pragma unroll
  for (int c=0;c<NC;++c)
    #pragma unroll
    for (int s=0;s<4;++s) acc[c][s] = (f32x4){0.f,0.f,0.f,0.f};
  #pragma unroll
  for (int kk=0;kk<4;++kk){
    short8 af[4];
    #pragma unroll
    for (int s=0;s<4;++s)
      af[s] = *reinterpret_cast<const short8*>(xs + rbase[s] + foff[kk]);
    #pragma unroll
    for (int c=0;c<NC;++c){
      short8 wf = wfrag[(((BC+c)*4+nt)*4+kk)*64 + l];
      #pragma unroll
      for (int s=0;s<4;++s)
        acc[c][s] = __builtin_amdgcn_mfma_f32_16x16x32_bf16(af[s], wf, acc[c][s], 0,0,0);
    }
  }
}

__device__ __forceinline__ float sx(float v, int mk){ return __shfl_xor(v, mk, 64); }

// ---- Kernel 2: fused GEMM + in-register scan ----
// grid (seg=32, b=32), 256 thr = 4 waves, wave = nt (16-m slice), 64 t/wave.
__global__ __launch_bounds__(256) void ls2t_main_k(const float* __restrict__ X,
                                                   const float* __restrict__ bias,
                                                   const short8* __restrict__ wfrag,
                                                   float* __restrict__ agg){
  const int seg = blockIdx.x;
  const int b   = blockIdx.y;
  const int tid = threadIdx.x;
  const int nt  = tid >> 6;
  const int l   = tid & 63;
  const int lr  = l & 15, lg = l >> 4;
  const int t0  = seg*64;

  // X tile bf16: addr = t*256 + (fblk ^ ((t>>2)&7))*16, fblk = f/8 (16B units)
  __shared__ __align__(16) char xs[16384];

  // stage: 2 passes; thread handles (t = tid&63, fpair = tid>>6 + p*4) = 64B
  #pragma unroll
  for (int p=0;p<2;++p){
    int t  = tid & 63;
    int fp = (tid >> 6) + p*4;            // 0..7
    const float* src = X + ((size_t)b*T_ + t0 + t)*F_ + fp*16;
    float4 v0 = *reinterpret_cast<const float4*>(src);
    float4 v1 = *reinterpret_cast<const float4*>(src+4);
    float4 v2 = *reinterpret_cast<const float4*>(src+8);
    float4 v3 = *reinterpret_cast<const float4*>(src+12);
    uint4 q0, q1;
    q0.x = (unsigned)f2bf(v0.x) | ((unsigned)f2bf(v0.y)<<16);
    q0.y = (unsigned)f2bf(v0.z) | ((unsigned)f2bf(v0.w)<<16);
    q0.z = (unsigned)f2bf(v1.x) | ((unsigned)f2bf(v1.y)<<16);
    q0.w = (unsigned)f2bf(v1.z) | ((unsigned)f2bf(v1.w)<<16);
    q1.x = (unsigned)f2bf(v2.x) | ((unsigned)f2bf(v2.y)<<16);
    q1.y = (unsigned)f2bf(v2.z) | ((unsigned)f2bf(v2.w)<<16);
    q1.z = (unsigned)f2bf(v3.x) | ((unsigned)f2bf(v3.y)<<16);
    q1.w = (unsigned)f2bf(v3.z) | ((unsigned)f2bf(v3.w)<<16);
    int sw = (t>>2)&7;
    *reinterpret_cast<uint4*>(xs + t*256 + ((fp*2  ) ^ sw)*16) = q0;
    *reinterpret_cast<uint4*>(xs + t*256 + ((fp*2+1) ^ sw)*16) = q1;
  }
  __syncthreads();

  // A-frag read addressing: row t = lr*4+s, fblk = kk*4+lg, swizzle lr&7
  int rbase[4], foff[4];
  #pragma unroll
  for (int s=0;s<4;++s)  rbase[s] = (lr*4+s)*256;
  #pragma unroll
  for (int kk=0;kk<4;++kk) foff[kk] = (((kk*4+lg) ^ (lr&7)))*16;

  const int mcol = nt*16 + lr;
  float* ob = agg + (((size_t)b*SEGS + seg)*20)*64 + mcol;

  // ================= level 1 (comp 0) =================
  {
    f32x4 acc[1][4];
    mfma_fill<1,0>(acc, xs, wfrag, rbase, foff, nt, l);
    float bz0 = bias[0*M_ + mcol];
    float S0 = 0.f;
    #pragma unroll
    for (int j=0;j<4;++j)
      #pragma unroll
      for (int s=0;s<4;++s) S0 += acc[0][s][j] + bz0;
    #pragma unroll
    for (int st=0; st<2; ++st) S0 += sx(S0, 16<<st);
    if (lg==0) ob[0*64] = S0;
  }
  // ================= level 2 (comps 1,2) =================
  {
    f32x4 acc[2][4];
    mfma_fill<2,1>(acc, xs, wfrag, rbase, foff, nt, l);
    float bz1 = bias[1*M_ + mcol], bz2 = bias[2*M_ + mcol];
    float S1=0.f,S2=0.f,I21=0.f;
    #pragma unroll
    for (int j=0;j<4;++j)
      #pragma unroll
      for (int s=0;s<4;++s){
        float a1 = acc[0][s][j] + bz1;
        float a2 = acc[1][s][j] + bz2;
        I21 += a2*S1; S1 += a1; S2 += a2;
      }
    #pragma unroll
    for (int st=0; st<2; ++st){
      int mk = 16<<st; bool up = (l & mk)!=0;
      float o1=sx(S1,mk), o2=sx(S2,mk), oI=sx(I21,mk);
      float A1=up?o1:S1, A2=up?o2:S2, AI=up?oI:I21;
      float B1=up?S1:o1, B2=up?S2:o2, BI=up?I21:oI;
      S1=A1+B1; S2=A2+B2; I21=AI+BI + A1*B2;
    }
    if (lg==0) ob[1*64]=S1; else if (lg==1) ob[2*64]=S2; else if (lg==2) ob[10*64]=I21;
  }
  // ================= level 3 (comps 3,4,5) =================
  {
    f32x4 acc[3][4];
    mfma_fill<3,3>(acc, xs, wfrag, rbase, foff, nt, l);
    float bz3 = bias[3*M_ + mcol], bz4 = bias[4*M_ + mcol], bz5 = bias[5*M_ + mcol];
    float S3=0.f,S4=0.f,S5=0.f,I43=0.f,I54=0.f,I543=0.f;
    #pragma unroll
    for (int j=0;j<4;++j)
      #pragma unroll
      for (int s=0;s<4;++s){
        float a3 = acc[0][s][j] + bz3;
        float a4 = acc[1][s][j] + bz4;
        float a5 = acc[2][s][j] + bz5;
        I543 += a5*I43; I54 += a5*S4; I43 += a4*S3;
        S3 += a3; S4 += a4; S5 += a5;
      }
    #pragma unroll
    for (int st=0; st<2; ++st){
      int mk = 16<<st; bool up = (l & mk)!=0;
      float o3=sx(S3,mk), o4=sx(S4,mk), o5=sx(S5,mk);
      float oA=sx(I43,mk), oB=sx(I54,mk), oC=sx(I543,mk);
      float A3=up?o3:S3, A4=up?o4:S4, A5=up?o5:S5;
      float AA=up?oA:I43, AB=up?oB:I54, AC=up?oC:I543;
      float B3=up?S3:o3, B4=up?S4:o4, B5=up?S5:o5;
      float BA=up?I43:oA, BB=up?I54:oB, BC_=up?I543:oC;
      float n43 = AA+BA + A3*B4;
      float n54 = AB+BB + A4*B5;
      float n543= AC+BC_ + AA*B5 + A3*BB;
      S3=A3+B3; S4=A4+B4; S5=A5+B5; I43=n43; I54=n54; I543=n543;
    }
    if      (lg==0){ ob[3*64]=S3;  ob[11*64]=I43; }
    else if (lg==1){ ob[4*64]=S4;  ob[12*64]=I54; }
    else if (lg==2){ ob[5*64]=S5;  ob[13*64]=I543; }
  }
  // ================= level 4 (comps 6,7,8,9) =================
  {
    f32x4 acc[4][4];
    mfma_fill<4,6>(acc, xs, wfrag, rbase, foff, nt, l);
    float bz6 = bias[6*M_ + mcol], bz7 = bias[7*M_ + mcol];
    float bz8 = bias[8*M_ + mcol], bz9 = bias[9*M_ + mcol];
    float S6=0.f,S7=0.f,S8=0.f,S9=0.f;
    float I76=0.f,I87=0.f,I98=0.f,I876=0.f,I987=0.f,I9876=0.f;
    #pragma unroll
    for (int j=0;j<4;++j)
      #pragma unroll
      for (int s=0;s<4;++s){
        float a6 = acc[0][s][j] + bz6;
        float a7 = acc[1][s][j] + bz7;
        float a8 = acc[2][s][j] + bz8;
        float a9 = acc[3][s][j] + bz9;
        I9876 += a9*I876; I987 += a9*I87; I98 += a9*S8;
        I876  += a8*I76;  I87  += a8*S7;
        I76   += a7*S6;
        S6 += a6; S7 += a7; S8 += a8; S9 += a9;
      }
    #pragma unroll
    for (int st=0; st<2; ++st){
      int mk = 16<<st; bool up = (l & mk)!=0;
      float o6=sx(S6,mk), o7=sx(S7,mk), o8=sx(S8,mk), o9=sx(S9,mk);
      float oA=sx(I76,mk), oB=sx(I87,mk), oC=sx(I98,mk);
      float oD=sx(I876,mk), oE=sx(I987,mk), oF=sx(I9876,mk);
      float A6=up?o6:S6, A7=up?o7:S7, A8=up?o8:S8, A9=up?o9:S9;
      float AA=up?oA:I76, AB=up?oB:I87, AC=up?oC:I98;
      float AD=up?oD:I876, AE=up?oE:I987, AF=up?oF:I9876;
      float B6=up?S6:o6, B7=up?S7:o7, B8=up?S8:o8, B9=up?S9:o9;
      float BA=up?I76:oA, BB=up?I87:oB, BC_=up?I98:oC;
      float BD=up?I876:oD, BE=up?I987:oE, BF=up?I9876:oF;
      float n76  = AA+BA + A6*B7;
      float n87  = AB+BB + A7*B8;
      float n98  = AC+BC_ + A8*B9;
      float n876 = AD+BD + AA*B8 + A6*BB;
      float n987 = AE+BE + AB*B9 + A7*BC_;
      float n9876= AF+BF + AD*B9 + AA*BC_ + A6*BE;
      S6=A6+B6; S7=A7+B7; S8=A8+B8; S9=A9+B9;
      I76=n76; I87=n87; I98=n98; I876=n876; I987=n987; I9876=n9876;
    }
    if      (lg==0){ ob[6*64]=S6; ob[14*64]=I76; ob[18*64]=I987; }
    else if (lg==1){ ob[7*64]=S7; ob[15*64]=I87; ob[19*64]=I9876; }
    else if (lg==2){ ob[8*64]=S8; ob[16*64]=I98; }
    else           { ob[9*64]=S9; ob[17*64]=I876; }
  }
}

// ---- Kernel 3: fold 32 segments per (b,m) ----
__global__ __launch_bounds__(256) void combine_k(const float* __restrict__ agg,
                                                 float* __restrict__ out){
  int g = blockIdx.x*256 + threadIdx.x;   // 0..2047
  int b = g >> 6, m = g & 63;
  const float* base = agg + ((size_t)b*SEGS*20)*64 + m;
  float y1=0,y2=0,y3=0,y4=0;
  float p1=0,q1=0,q2=0,r1=0,r2=0,r3=0;
  #pragma unroll 4
  for (int s=0;s<SEGS;++s){
    const float* a = base + (size_t)s*20*64;
    float S0=a[0],    S1=a[64],   S2=a[128],  S3=a[192],  S4=a[256];
    float S5=a[320],  S6=a[384],  S7=a[448],  S8=a[512],  S9=a[576];
    float I21=a[640], I43=a[704], I54=a[768], I543=a[832];
    float I76=a[896], I87=a[960], I98=a[1024];
    float I876=a[1088], I987=a[1152], I9876=a[1216];
    y1 += S0;
    y2 += p1*S2 + I21;
    y3 += q2*S5 + q1*I54 + I543;
    y4 += r3*S9 + r2*I98 + r1*I987 + I9876;
    r3 += r2*S8 + r1*I87 + I876;
    r2 += r1*S7 + I76;
    r1 += S6;
    q2 += q1*S4 + I43;
    q1 += S3;
    p1 += S1;
  }
  out[(b*4+0)*64+m]=y1;
  out[(b*4+1)*64+m]=y2;
  out[(b*4+2)*64+m]=y3;
  out[(b*4+3)*64+m]=y4;
}

extern "C" void kernel_launch(void* const* d_in, const int* in_sizes, int n_in,
                              void* d_out, int out_size, void* d_ws, size_t ws_size,
                              hipStream_t stream){
  const float* X    = (const float*)d_in[0];   // [32,2048,128]
  const float* Wk   = (const float*)d_in[1];   // [10,128,64]
  const float* bias = (const float*)d_in[2];   // [10,64]
  float* out = (float*)d_out;                  // [32,4,64]

  uint4* wsw = (uint4*)d_ws;                                 // 160 KB W frags
  float* agg = (float*)((char*)d_ws + (1u<<20));             // 5.25 MB aggregates

  hipLaunchKernelGGL(prep_w_k,    dim3(40),     dim3(256), 0, stream, Wk, wsw);
  hipLaunchKernelGGL(ls2t_main_k, dim3(32,32),  dim3(256), 0, stream,
                     X, bias, (const short8*)d_ws, agg);
  hipLaunchKernelGGL(combine_k,   dim3(8),      dim3(256), 0, stream, agg, out);
}